// Round 1
// baseline (391.068 us; speedup 1.0000x reference)
//
#include <hip/hip_runtime.h>
#include <hip/hip_bf16.h>

typedef __bf16 bf16x8 __attribute__((ext_vector_type(8)));
typedef float f32x4 __attribute__((ext_vector_type(4)));
typedef unsigned short u16;
typedef unsigned short us4 __attribute__((ext_vector_type(4)));
typedef unsigned int u32;

// ---------- bf16 helpers (RNE) ----------
__device__ __forceinline__ u16 f2bf(float x) {
  union { float f; u32 u; } v; v.f = x;
  u32 r = v.u + 0x7FFFu + ((v.u >> 16) & 1u);
  return (u16)(r >> 16);
}
__device__ __forceinline__ float bf2f(u16 h) {
  union { u32 u; float f; } v; v.u = ((u32)h) << 16;
  return v.f;
}

__device__ __forceinline__ void glds16(const void* g, void* l) {
  __builtin_amdgcn_global_load_lds(
      (const __attribute__((address_space(1))) void*)g,
      (__attribute__((address_space(3))) void*)l, 16, 0, 0);
}

// ---------- universal B^T GEMM: C[M,N] = A[M,K] * B[N,K]^T ----------
// NSEG==3: A packed [hi|lo] (lda=2*K0), B packed [hi|lo]; computes
//          Ah*Bh + Al*Bh + Ah*Bl (bf16 hi/lo fp32-emulation).
// EPI: 0 = fp32 store (scores)
//      1 = +bias, split hi/lo bf16 into C[row][col] and C[row][col+1024]
//      2 = bf16 store (feed/attended)
//      3 = +bias, tanh, fp32 store (final output)
template<int NSEG, int EPI>
__global__ __launch_bounds__(256)
void gemm_bt(const u16* __restrict__ A, const u16* __restrict__ B,
             void* __restrict__ Cout, const float* __restrict__ bias,
             int K0, int lda, int ldb, int ldc,
             long sA, long sB, long sC)
{
  __shared__ __align__(16) u16 As[128 * 32];
  __shared__ __align__(16) u16 Bs[128 * 32];

  const int bz   = blockIdx.z;
  const int brow = blockIdx.x * 128;
  const int bcol = blockIdx.y * 128;
  const int tid  = threadIdx.x;
  const int wid  = tid >> 6;
  const int lane = tid & 63;
  const int wr   = wid >> 1, wc = wid & 1;

  const u16* Ab = A + (long)bz * sA + (long)brow * lda;
  const u16* Bb = B + (long)bz * sB + (long)bcol * ldb;

  f32x4 acc[4][4];
#pragma unroll
  for (int m = 0; m < 4; ++m)
#pragma unroll
    for (int n = 0; n < 4; ++n) acc[m][n] = (f32x4){0.f, 0.f, 0.f, 0.f};

  // staging geometry: wave wid stages rows [wid*32, wid*32+32) of each tile
  const int srow = wid * 32 + (lane >> 2);
  const int scol = (lane & 3) * 8;
  u16* lA0 = As + wid * 32 * 32;
  u16* lA1 = lA0 + 16 * 32;
  u16* lB0 = Bs + wid * 32 * 32;
  u16* lB1 = lB0 + 16 * 32;

  const int lr = lane & 15;          // operand row/col within fragment
  const int lk = (lane >> 4) * 8;    // k-offset within fragment

  for (int seg = 0; seg < NSEG; ++seg) {
    const u16* Aseg = Ab + ((NSEG == 3 && seg == 1) ? K0 : 0);
    const u16* Bseg = Bb + ((NSEG == 3 && seg == 2) ? K0 : 0);
    for (int kt = 0; kt < K0; kt += 32) {
      const u16* ga = Aseg + (long)srow * lda + kt + scol;
      const u16* gb = Bseg + (long)srow * ldb + kt + scol;
      glds16(ga, lA0);
      glds16(ga + (long)16 * lda, lA1);
      glds16(gb, lB0);
      glds16(gb + (long)16 * ldb, lB1);
      __syncthreads();   // compiler emits vmcnt(0) drain before barrier

      bf16x8 af[4], bfr[4];
#pragma unroll
      for (int m = 0; m < 4; ++m)
        af[m] = *(const bf16x8*)(As + (wr * 64 + m * 16 + lr) * 32 + lk);
#pragma unroll
      for (int n = 0; n < 4; ++n)
        bfr[n] = *(const bf16x8*)(Bs + (wc * 64 + n * 16 + lr) * 32 + lk);
#pragma unroll
      for (int m = 0; m < 4; ++m)
#pragma unroll
        for (int n = 0; n < 4; ++n)
          acc[m][n] = __builtin_amdgcn_mfma_f32_16x16x32_bf16(af[m], bfr[n], acc[m][n], 0, 0, 0);
      __syncthreads();   // all reads done before next stage overwrites
    }
  }

  // epilogue: C/D layout col=lane&15, row=(lane>>4)*4+reg  [m89-verified]
  const int crow0 = brow + wr * 64;
  const int ccol0 = bcol + wc * 64;
  const int orow  = (lane >> 4) * 4;
  const int ocol  = lane & 15;

#pragma unroll
  for (int m = 0; m < 4; ++m) {
#pragma unroll
    for (int n = 0; n < 4; ++n) {
      const int col = ccol0 + n * 16 + ocol;
      float bv = 0.f;
      if (EPI == 1 || EPI == 3) bv = bias[col];
#pragma unroll
      for (int j = 0; j < 4; ++j) {
        const int row = crow0 + m * 16 + orow + j;
        float v = acc[m][n][j] + bv;
        if (EPI == 0) {
          ((float*)Cout)[(long)bz * sC + (long)row * ldc + col] = v;
        } else if (EPI == 1) {
          u16 hi = f2bf(v);
          u16 lo = f2bf(v - bf2f(hi));
          u16* Co = (u16*)Cout + (long)bz * sC + (long)row * ldc;
          Co[col] = hi;
          Co[col + 1024] = lo;
        } else if (EPI == 2) {
          ((u16*)Cout)[(long)bz * sC + (long)row * ldc + col] = f2bf(v);
        } else {
          ((float*)Cout)[(long)bz * sC + (long)row * ldc + col] = tanhf(v);
        }
      }
    }
  }
}

// ---------- fp32 -> [hi|lo] bf16 pack (rows x 1024 -> rows x 2048) ----------
// Optionally also writes hi into FQ[row][1024+col] (query -> feed right half).
__global__ __launch_bounds__(256)
void split_pack(const float* __restrict__ X, u16* __restrict__ P,
                u16* __restrict__ FQ, long n4)
{
  long i = (long)blockIdx.x * 256 + threadIdx.x;
  const long stride = (long)gridDim.x * 256;
  for (; i < n4; i += stride) {
    float4 x = ((const float4*)X)[i];
    long e = i * 4;
    long row = e >> 10;
    int col = (int)(e & 1023);
    float xs[4] = {x.x, x.y, x.z, x.w};
    u16 h[4], l[4];
#pragma unroll
    for (int j = 0; j < 4; ++j) {
      h[j] = f2bf(xs[j]);
      l[j] = f2bf(xs[j] - bf2f(h[j]));
    }
    us4 hv = {h[0], h[1], h[2], h[3]};
    us4 lv = {l[0], l[1], l[2], l[3]};
    *(us4*)(P + row * 2048 + col) = hv;
    *(us4*)(P + row * 2048 + 1024 + col) = lv;
    if (FQ) *(us4*)(FQ + row * 2048 + 1024 + col) = hv;
  }
}

// ---------- values: [hi|lo] pack (row-major) + bf16 transpose ----------
__global__ __launch_bounds__(256)
void conv_values(const float* __restrict__ V, u16* __restrict__ Vp,
                 u16* __restrict__ VT)
{
  __shared__ u16 tile[64][68];
  const int b  = blockIdx.z;
  const int d0 = blockIdx.x * 64;
  const int k0 = blockIdx.y * 64;
  const int t  = threadIdx.x;
  const int tr = t >> 4;            // 0..15
  const int tc = (t & 15) * 4;      // 0..60
  const float* Vb = V + (long)b * (1024L * 1024);
  u16* Vpb = Vp + (long)b * (1024L * 2048);
  u16* VTb = VT + (long)b * (1024L * 1024);

#pragma unroll
  for (int i = 0; i < 4; ++i) {
    int k = tr + i * 16;
    float4 x = *(const float4*)(Vb + (long)(k0 + k) * 1024 + d0 + tc);
    float xs[4] = {x.x, x.y, x.z, x.w};
    u16 h[4], l[4];
#pragma unroll
    for (int j = 0; j < 4; ++j) {
      h[j] = f2bf(xs[j]);
      l[j] = f2bf(xs[j] - bf2f(h[j]));
      tile[k][tc + j] = h[j];
    }
    us4 hv = {h[0], h[1], h[2], h[3]};
    us4 lv = {l[0], l[1], l[2], l[3]};
    *(us4*)(Vpb + (long)(k0 + k) * 2048 + d0 + tc) = hv;
    *(us4*)(Vpb + (long)(k0 + k) * 2048 + 1024 + d0 + tc) = lv;
  }
  __syncthreads();
#pragma unroll
  for (int i = 0; i < 4; ++i) {
    int d = tr + i * 16;
    int k = tc;
    us4 o = {tile[k][d], tile[k + 1][d], tile[k + 2][d], tile[k + 3][d]};
    *(us4*)(VTb + (long)(d0 + d) * 1024 + k0 + k) = o;
  }
}

// ---------- plain fp32 -> bf16 cast ----------
__global__ __launch_bounds__(256)
void conv_cast(const float* __restrict__ X, u16* __restrict__ Y, long n4)
{
  long i = (long)blockIdx.x * 256 + threadIdx.x;
  const long stride = (long)gridDim.x * 256;
  for (; i < n4; i += stride) {
    float4 x = ((const float4*)X)[i];
    us4 o = {f2bf(x.x), f2bf(x.y), f2bf(x.z), f2bf(x.w)};
    *(us4*)(Y + i * 4) = o;
  }
}

// ---------- row softmax: fp32 scores[8192][1024] -> bf16 attn ----------
__global__ __launch_bounds__(256)
void softmax_rows(const float* __restrict__ S, u16* __restrict__ A)
{
  const long row = blockIdx.x;
  const float* src = S + row * 1024;
  const int t = threadIdx.x;
  const int lane = t & 63, wid = t >> 6;
  float4 v = ((const float4*)src)[t];
  float m = fmaxf(fmaxf(v.x, v.y), fmaxf(v.z, v.w));
#pragma unroll
  for (int off = 32; off >= 1; off >>= 1)
    m = fmaxf(m, __shfl_xor(m, off));
  __shared__ float redm[4];
  if (lane == 0) redm[wid] = m;
  __syncthreads();
  m = fmaxf(fmaxf(redm[0], redm[1]), fmaxf(redm[2], redm[3]));
  float e0 = __expf(v.x - m), e1 = __expf(v.y - m);
  float e2 = __expf(v.z - m), e3 = __expf(v.w - m);
  float s = e0 + e1 + e2 + e3;
#pragma unroll
  for (int off = 32; off >= 1; off >>= 1)
    s += __shfl_xor(s, off);
  __shared__ float reds[4];
  if (lane == 0) reds[wid] = s;
  __syncthreads();
  s = reds[0] + reds[1] + reds[2] + reds[3];
  float inv = 1.0f / s;
  us4 o = {f2bf(e0 * inv), f2bf(e1 * inv), f2bf(e2 * inv), f2bf(e3 * inv)};
  ((us4*)(A + row * 1024))[t] = o;
}

extern "C" void kernel_launch(void* const* d_in, const int* in_sizes, int n_in,
                              void* d_out, int out_size, void* d_ws, size_t ws_size,
                              hipStream_t stream)
{
  const float* query  = (const float*)d_in[0];  // [8,1024,1024]
  const float* values = (const float*)d_in[1];  // [8,1024,1024]
  const float* W1     = (const float*)d_in[2];  // [1024,1024]
  const float* b1     = (const float*)d_in[3];  // [1024]
  const float* W2     = (const float*)d_in[4];  // [1024,2048]
  const float* b2     = (const float*)d_in[5];  // [1024]
  float* out = (float*)d_out;                   // [8,1024,1024]

  char* ws = (char*)d_ws;
  const long MB = 1024L * 1024;
  // layout (152 MB total, with lifetime aliasing):
  u16*   W1p    = (u16*)(ws);              //   4 MB  W1 [hi|lo]
  u16*   W2b    = (u16*)(ws + 4 * MB);     //   4 MB  W2 bf16
  u16*   Aq     = (u16*)(ws + 8 * MB);     //  32 MB  query [hi|lo]   (dead after GEMM1)
  float* scores = (float*)(ws + 8 * MB);   //  32 MB  aliases Aq
  u16*   qr     = (u16*)(ws + 40 * MB);    //  32 MB  q_resize [hi|lo] (dead after GEMM2)
  u16*   attn   = (u16*)(ws + 40 * MB);    //  16 MB  aliases qr
  u16*   Vp     = (u16*)(ws + 72 * MB);    //  32 MB  values [hi|lo]
  u16*   VT     = (u16*)(ws + 104 * MB);   //  16 MB  values^T bf16
  u16*   feed   = (u16*)(ws + 120 * MB);   //  32 MB  [attended | query] bf16

  // conversions
  split_pack<<<dim3(2048), dim3(256), 0, stream>>>(query, Aq, feed, (8192L * 1024) / 4);
  split_pack<<<dim3(1024), dim3(256), 0, stream>>>(W1, W1p, (u16*)nullptr, (1024L * 1024) / 4);
  conv_values<<<dim3(16, 16, 8), dim3(256), 0, stream>>>(values, Vp, VT);
  conv_cast<<<dim3(1024), dim3(256), 0, stream>>>(W2, W2b, (1024L * 2048) / 4);

  // GEMM1: q_resize = query @ W1^T + b1  -> qr [hi|lo]   (hi/lo split, K=3*1024)
  gemm_bt<3, 1><<<dim3(64, 8, 1), dim3(256), 0, stream>>>(
      Aq, W1p, qr, b1, 1024, 2048, 2048, 2048, 0L, 0L, 0L);

  // GEMM2: scores[b] = qr[b] @ values[b]^T               (hi/lo split, batched)
  gemm_bt<3, 0><<<dim3(8, 8, 8), dim3(256), 0, stream>>>(
      qr, Vp, scores, (const float*)nullptr, 1024, 2048, 2048, 1024,
      1024L * 2048, 1024L * 2048, 1024L * 1024);

  // softmax over keys -> bf16 attn
  softmax_rows<<<dim3(8192), dim3(256), 0, stream>>>(scores, attn);

  // GEMM3: attended[b] = attn[b] @ values[b] -> feed[:, 0:1024] bf16
  gemm_bt<1, 2><<<dim3(8, 8, 8), dim3(256), 0, stream>>>(
      attn, VT, feed, (const float*)nullptr, 1024, 1024, 1024, 2048,
      1024L * 1024, 1024L * 1024, 1024L * 2048);

  // GEMM4: out = tanh(feed @ W2^T + b2)
  gemm_bt<1, 3><<<dim3(64, 8, 1), dim3(256), 0, stream>>>(
      feed, W2b, out, b2, 2048, 2048, 2048, 1024, 0L, 0L, 0L);
}

// Round 2
// 390.575 us; speedup vs baseline: 1.0013x; 1.0013x over previous
//
#include <hip/hip_runtime.h>
#include <hip/hip_bf16.h>

typedef __bf16 bf16x8 __attribute__((ext_vector_type(8)));
typedef float f32x4 __attribute__((ext_vector_type(4)));
typedef unsigned short u16;
typedef unsigned short us4 __attribute__((ext_vector_type(4)));
typedef unsigned int u32;

// ---------- bf16 helpers (RNE) ----------
__device__ __forceinline__ u16 f2bf(float x) {
  union { float f; u32 u; } v; v.f = x;
  u32 r = v.u + 0x7FFFu + ((v.u >> 16) & 1u);
  return (u16)(r >> 16);
}
__device__ __forceinline__ float bf2f(u16 h) {
  union { u32 u; float f; } v; v.u = ((u32)h) << 16;
  return v.f;
}

__device__ __forceinline__ void glds16(const void* g, void* l) {
  __builtin_amdgcn_global_load_lds(
      (const __attribute__((address_space(1))) void*)g,
      (__attribute__((address_space(3))) void*)l, 16, 0, 0);
}

// ---------- universal B^T GEMM: C[M,N] = A[M,K] * B[N,K]^T ----------
// BM=256, BN=128, BK=64 double-buffered, 8 waves (4x2), per-wave 64x64.
// 2-phase loop: stage(next) issued BEFORE compute(cur); ONE barrier/K-step.
// Grid: 1D, nwg = nz*nx*ny = 256 blocks exactly (1 block/CU), XCD-chunk swizzle.
// NSEG==3: A,B packed [hi|lo] (ld=2*K0, K0 must be 1024): Ah*Bh + Al*Bh + Ah*Bl.
// EPI: 0 = fp32 store (scores)
//      1 = +bias, split hi/lo bf16 into C[row][col] and C[row][col+1024]
//      2 = bf16 store (feed/attended)
//      3 = +bias, tanh, fp32 store (final output)
template<int NSEG, int EPI>
__global__ __launch_bounds__(512)
void gemm_bt(const u16* __restrict__ A, const u16* __restrict__ B,
             void* __restrict__ Cout, const float* __restrict__ bias,
             int K0, int lda, int ldb, int ldc,
             long sA, long sB, long sC, int nx, int ny)
{
  // [buf][khalf][row*32+col] — 64B row stride (2-way bank alias = free, m136)
  __shared__ __align__(16) u16 As[2][2][256 * 32];   // 64 KB
  __shared__ __align__(16) u16 Bs[2][2][128 * 32];   // 32 KB

  // bijective XCD-chunk swizzle (nwg=256, 8 XCDs, 32-block chunks)
  const int d = blockIdx.x;
  const int L = ((d & 7) << 5) | (d >> 3);
  const int nxy = nx * ny;
  const int bz = L / nxy;
  const int rr = L - bz * nxy;
  const int bx = rr / ny;
  const int by = rr - bx * ny;
  const int brow = bx * 256;
  const int bcol = by * 128;

  const int tid  = threadIdx.x;
  const int wid  = tid >> 6;       // 0..7
  const int lane = tid & 63;
  const int wr   = wid >> 1;       // 0..3  (64-row block)
  const int wc   = wid & 1;        // 0..1  (64-col block)

  const u16* Ab = A + (long)bz * sA + (long)brow * lda;
  const u16* Bb = B + (long)bz * sB + (long)bcol * ldb;

  f32x4 acc[4][4];
#pragma unroll
  for (int m = 0; m < 4; ++m)
#pragma unroll
    for (int n = 0; n < 4; ++n) acc[m][n] = (f32x4){0.f, 0.f, 0.f, 0.f};

  // staging: each glds16 = 64 lanes x 16B = 16 rows x 64B (32 u16 cols)
  const int sr = lane >> 2;          // row within 16-row group
  const int sc = (lane & 3) * 8;     // col chunk within 32-col half

  const int ksteps = (NSEG == 3) ? 16 : (K0 >> 6);
  const int NT = NSEG * ksteps;

  auto stage = [&](int buf, int t) {
    int seg, kt;
    if (NSEG == 3) { seg = t >> 4; kt = (t & 15) << 6; }
    else           { seg = 0;      kt = t << 6; }
    const u16* Aseg = Ab + ((NSEG == 3 && seg == 1) ? K0 : 0) + kt;
    const u16* Bseg = Bb + ((NSEG == 3 && seg == 2) ? K0 : 0) + kt;
#pragma unroll
    for (int h = 0; h < 2; ++h) {
#pragma unroll
      for (int i = 0; i < 2; ++i) {  // A: wave stages rows [wid*32, wid*32+32)
        const int row = wid * 32 + i * 16;
        glds16(Aseg + (long)(row + sr) * lda + h * 32 + sc,
               As[buf][h] + row * 32);
      }
      {                              // B: wave stages rows [wid*16, wid*16+16)
        const int row = wid * 16;
        glds16(Bseg + (long)(row + sr) * ldb + h * 32 + sc,
               Bs[buf][h] + row * 32);
      }
    }
  };

  const int lr = lane & 15;          // fragment row/col
  const int lk = (lane >> 4) * 8;    // k-offset within 32-col sub-tile

  stage(0, 0);
  __syncthreads();                   // drain prologue stage

  int buf = 0;
  for (int t = 0; t < NT; ++t) {
    if (t + 1 < NT) stage(buf ^ 1, t + 1);   // loads in flight during compute
#pragma unroll
    for (int h = 0; h < 2; ++h) {
      bf16x8 af[4], bfr[4];
#pragma unroll
      for (int m = 0; m < 4; ++m)
        af[m] = *(const bf16x8*)(As[buf][h] + (wr * 64 + m * 16 + lr) * 32 + lk);
#pragma unroll
      for (int n = 0; n < 4; ++n)
        bfr[n] = *(const bf16x8*)(Bs[buf][h] + (wc * 64 + n * 16 + lr) * 32 + lk);
#pragma unroll
      for (int m = 0; m < 4; ++m)
#pragma unroll
        for (int n = 0; n < 4; ++n)
          acc[m][n] = __builtin_amdgcn_mfma_f32_16x16x32_bf16(af[m], bfr[n], acc[m][n], 0, 0, 0);
    }
    __syncthreads();   // drains vmcnt(0): next buf staged; all reads of buf done
    buf ^= 1;
  }

  // epilogue: C/D layout col=lane&15, row=(lane>>4)*4+reg  [m89-verified]
  const int crow0 = brow + wr * 64;
  const int ccol0 = bcol + wc * 64;
  const int orow  = (lane >> 4) * 4;
  const int ocol  = lane & 15;

#pragma unroll
  for (int m = 0; m < 4; ++m) {
#pragma unroll
    for (int n = 0; n < 4; ++n) {
      const int col = ccol0 + n * 16 + ocol;
      float bv = 0.f;
      if (EPI == 1 || EPI == 3) bv = bias[col];
#pragma unroll
      for (int j = 0; j < 4; ++j) {
        const int row = crow0 + m * 16 + orow + j;
        float v = acc[m][n][j] + bv;
        if (EPI == 0) {
          ((float*)Cout)[(long)bz * sC + (long)row * ldc + col] = v;
        } else if (EPI == 1) {
          u16 hi = f2bf(v);
          u16 lo = f2bf(v - bf2f(hi));
          u16* Co = (u16*)Cout + (long)bz * sC + (long)row * ldc;
          Co[col] = hi;
          Co[col + 1024] = lo;
        } else if (EPI == 2) {
          ((u16*)Cout)[(long)bz * sC + (long)row * ldc + col] = f2bf(v);
        } else {
          ((float*)Cout)[(long)bz * sC + (long)row * ldc + col] = tanhf(v);
        }
      }
    }
  }
}

// ---------- fp32 -> [hi|lo] bf16 pack (rows x 1024 -> rows x 2048) ----------
__global__ __launch_bounds__(256)
void split_pack(const float* __restrict__ X, u16* __restrict__ P,
                u16* __restrict__ FQ, long n4)
{
  long i = (long)blockIdx.x * 256 + threadIdx.x;
  const long stride = (long)gridDim.x * 256;
  for (; i < n4; i += stride) {
    float4 x = ((const float4*)X)[i];
    long e = i * 4;
    long row = e >> 10;
    int col = (int)(e & 1023);
    float xs[4] = {x.x, x.y, x.z, x.w};
    u16 h[4], l[4];
#pragma unroll
    for (int j = 0; j < 4; ++j) {
      h[j] = f2bf(xs[j]);
      l[j] = f2bf(xs[j] - bf2f(h[j]));
    }
    us4 hv = {h[0], h[1], h[2], h[3]};
    us4 lv = {l[0], l[1], l[2], l[3]};
    *(us4*)(P + row * 2048 + col) = hv;
    *(us4*)(P + row * 2048 + 1024 + col) = lv;
    if (FQ) *(us4*)(FQ + row * 2048 + 1024 + col) = hv;
  }
}

// ---------- values: [hi|lo] pack (row-major) + bf16 transpose ----------
__global__ __launch_bounds__(256)
void conv_values(const float* __restrict__ V, u16* __restrict__ Vp,
                 u16* __restrict__ VT)
{
  __shared__ u16 tile[64][68];
  const int b  = blockIdx.z;
  const int d0 = blockIdx.x * 64;
  const int k0 = blockIdx.y * 64;
  const int t  = threadIdx.x;
  const int tr = t >> 4;            // 0..15
  const int tc = (t & 15) * 4;      // 0..60
  const float* Vb = V + (long)b * (1024L * 1024);
  u16* Vpb = Vp + (long)b * (1024L * 2048);
  u16* VTb = VT + (long)b * (1024L * 1024);

#pragma unroll
  for (int i = 0; i < 4; ++i) {
    int k = tr + i * 16;
    float4 x = *(const float4*)(Vb + (long)(k0 + k) * 1024 + d0 + tc);
    float xs[4] = {x.x, x.y, x.z, x.w};
    u16 h[4], l[4];
#pragma unroll
    for (int j = 0; j < 4; ++j) {
      h[j] = f2bf(xs[j]);
      l[j] = f2bf(xs[j] - bf2f(h[j]));
      tile[k][tc + j] = h[j];
    }
    us4 hv = {h[0], h[1], h[2], h[3]};
    us4 lv = {l[0], l[1], l[2], l[3]};
    *(us4*)(Vpb + (long)(k0 + k) * 2048 + d0 + tc) = hv;
    *(us4*)(Vpb + (long)(k0 + k) * 2048 + 1024 + d0 + tc) = lv;
  }
  __syncthreads();
#pragma unroll
  for (int i = 0; i < 4; ++i) {
    int d = tr + i * 16;
    int k = tc;
    us4 o = {tile[k][d], tile[k + 1][d], tile[k + 2][d], tile[k + 3][d]};
    *(us4*)(VTb + (long)(d0 + d) * 1024 + k0 + k) = o;
  }
}

// ---------- plain fp32 -> bf16 cast ----------
__global__ __launch_bounds__(256)
void conv_cast(const float* __restrict__ X, u16* __restrict__ Y, long n4)
{
  long i = (long)blockIdx.x * 256 + threadIdx.x;
  const long stride = (long)gridDim.x * 256;
  for (; i < n4; i += stride) {
    float4 x = ((const float4*)X)[i];
    us4 o = {f2bf(x.x), f2bf(x.y), f2bf(x.z), f2bf(x.w)};
    *(us4*)(Y + i * 4) = o;
  }
}

// ---------- row softmax: fp32 scores[8192][1024] -> bf16 attn ----------
__global__ __launch_bounds__(256)
void softmax_rows(const float* __restrict__ S, u16* __restrict__ A)
{
  const long row = blockIdx.x;
  const float* src = S + row * 1024;
  const int t = threadIdx.x;
  const int lane = t & 63, wid = t >> 6;
  float4 v = ((const float4*)src)[t];
  float m = fmaxf(fmaxf(v.x, v.y), fmaxf(v.z, v.w));
#pragma unroll
  for (int off = 32; off >= 1; off >>= 1)
    m = fmaxf(m, __shfl_xor(m, off));
  __shared__ float redm[4];
  if (lane == 0) redm[wid] = m;
  __syncthreads();
  m = fmaxf(fmaxf(redm[0], redm[1]), fmaxf(redm[2], redm[3]));
  float e0 = __expf(v.x - m), e1 = __expf(v.y - m);
  float e2 = __expf(v.z - m), e3 = __expf(v.w - m);
  float s = e0 + e1 + e2 + e3;
#pragma unroll
  for (int off = 32; off >= 1; off >>= 1)
    s += __shfl_xor(s, off);
  __shared__ float reds[4];
  if (lane == 0) reds[wid] = s;
  __syncthreads();
  s = reds[0] + reds[1] + reds[2] + reds[3];
  float inv = 1.0f / s;
  us4 o = {f2bf(e0 * inv), f2bf(e1 * inv), f2bf(e2 * inv), f2bf(e3 * inv)};
  ((us4*)(A + row * 1024))[t] = o;
}

extern "C" void kernel_launch(void* const* d_in, const int* in_sizes, int n_in,
                              void* d_out, int out_size, void* d_ws, size_t ws_size,
                              hipStream_t stream)
{
  const float* query  = (const float*)d_in[0];  // [8,1024,1024]
  const float* values = (const float*)d_in[1];  // [8,1024,1024]
  const float* W1     = (const float*)d_in[2];  // [1024,1024]
  const float* b1     = (const float*)d_in[3];  // [1024]
  const float* W2     = (const float*)d_in[4];  // [1024,2048]
  const float* b2     = (const float*)d_in[5];  // [1024]
  float* out = (float*)d_out;                   // [8,1024,1024]

  char* ws = (char*)d_ws;
  const long MB = 1024L * 1024;
  // layout (152 MB total, with lifetime aliasing):
  u16*   W1p    = (u16*)(ws);              //   4 MB  W1 [hi|lo]
  u16*   W2b    = (u16*)(ws + 4 * MB);     //   4 MB  W2 bf16
  u16*   Aq     = (u16*)(ws + 8 * MB);     //  32 MB  query [hi|lo]   (dead after GEMM1)
  float* scores = (float*)(ws + 8 * MB);   //  32 MB  aliases Aq
  u16*   qr     = (u16*)(ws + 40 * MB);    //  32 MB  q_resize [hi|lo] (dead after GEMM2)
  u16*   attn   = (u16*)(ws + 40 * MB);    //  16 MB  aliases qr
  u16*   Vp     = (u16*)(ws + 72 * MB);    //  32 MB  values [hi|lo]
  u16*   VT     = (u16*)(ws + 104 * MB);   //  16 MB  values^T bf16
  u16*   feed   = (u16*)(ws + 120 * MB);   //  32 MB  [attended | query] bf16

  // conversions
  split_pack<<<dim3(2048), dim3(256), 0, stream>>>(query, Aq, feed, (8192L * 1024) / 4);
  split_pack<<<dim3(1024), dim3(256), 0, stream>>>(W1, W1p, (u16*)nullptr, (1024L * 1024) / 4);
  conv_values<<<dim3(16, 16, 8), dim3(256), 0, stream>>>(values, Vp, VT);
  conv_cast<<<dim3(1024), dim3(256), 0, stream>>>(W2, W2b, (1024L * 2048) / 4);

  // GEMM1: q_resize = query @ W1^T + b1  -> qr [hi|lo]   (hi/lo, virt-K=3072)
  gemm_bt<3, 1><<<dim3(256), dim3(512), 0, stream>>>(
      Aq, W1p, qr, b1, 1024, 2048, 2048, 2048, 0L, 0L, 0L, 32, 8);

  // GEMM2: scores[b] = qr[b] @ values[b]^T               (hi/lo, batched)
  gemm_bt<3, 0><<<dim3(256), dim3(512), 0, stream>>>(
      qr, Vp, scores, (const float*)nullptr, 1024, 2048, 2048, 1024,
      1024L * 2048, 1024L * 2048, 1024L * 1024, 4, 8);

  // softmax over keys -> bf16 attn
  softmax_rows<<<dim3(8192), dim3(256), 0, stream>>>(scores, attn);

  // GEMM3: attended[b] = attn[b] @ values[b] -> feed[:, 0:1024] bf16
  gemm_bt<1, 2><<<dim3(256), dim3(512), 0, stream>>>(
      attn, VT, feed, (const float*)nullptr, 1024, 1024, 1024, 2048,
      1024L * 1024, 1024L * 1024, 1024L * 2048, 4, 8);

  // GEMM4: out = tanh(feed @ W2^T + b2)
  gemm_bt<1, 3><<<dim3(256), dim3(512), 0, stream>>>(
      feed, W2b, out, b2, 2048, 2048, 2048, 1024, 0L, 0L, 0L, 32, 8);
}